// Round 1
// 69.635 us; speedup vs baseline: 1.0579x; 1.0579x over previous
//
#include <hip/hip_runtime.h>
#include <stdint.h>

// QuadraticConv2DTranspose via per-parity-class bf16 MFMA GEMM.
// Single-dispatch, zero-LDS, zero-barrier version.
//
// Bed-of-nails stride-2 upsample => per output-parity class only 2/5/5/14 of
// the 55 features are live. Cast as 4 GEMMs:
//   out[m,n] = sum_k F[m,k] * W[k,n],  k = f*64 + c
// with the bias row (L=54) folded in as an extra "ones" feature, so no
// separate bias kernel and no workspace use.
//
// Rationale vs previous version (73.7 us): kern (901 KB) and x (2.1 MB) are
// both L2-resident; staging W through LDS with a barrier per feature was a
// pure serialization chain (load->cvt->ds_write->barrier->ds_read->mfma, x28
// for class 3). Now every wave is fully independent: B-frags are 16 dword
// loads per feature off one base VGPR (imm offsets 0..1792B), A-planes are
// coalesced float4 loads from x, conversions use packed v_cvt_pk_bf16_f32
// via __builtin_convertvector. No __syncthreads anywhere.

typedef __attribute__((ext_vector_type(8))) short short8;
typedef __attribute__((ext_vector_type(8))) float floatx8;
typedef __attribute__((ext_vector_type(8))) __bf16 bf16x8;
typedef __attribute__((ext_vector_type(4))) float floatx4;

namespace {
constexpr int kBiasL = 54;
}

// Per-class tables. Patch value j = x[hi+DY[j], wi+DX[j]].
// Feature f: kernel row L[f], value v[A[f]]*v[Bb[f]]; Bb[f]==NV -> linear (v[A]).
template <int CLS> struct CI;
template <> struct CI<0> {  // ho even, wo even
  static constexpr int NV = 1, NF = 2;
  static constexpr int L[NF] = {30, 49};
  static constexpr int A[NF] = {0, 0};
  static constexpr int Bb[NF] = {0, 1};
  static constexpr int DY[NV] = {0};
  static constexpr int DX[NV] = {0};
};
template <> struct CI<1> {  // ho even, wo odd
  static constexpr int NV = 2, NF = 5;
  static constexpr int L[NF] = {24, 26, 35, 48, 50};
  static constexpr int A[NF] = {0, 0, 1, 0, 1};
  static constexpr int Bb[NF] = {0, 1, 1, 2, 2};
  static constexpr int DY[NV] = {0, 0};
  static constexpr int DX[NV] = {0, 1};
};
template <> struct CI<2> {  // ho odd, wo even
  static constexpr int NV = 2, NF = 5;
  static constexpr int L[NF] = {9, 15, 42, 46, 52};
  static constexpr int A[NF] = {0, 0, 1, 0, 1};
  static constexpr int Bb[NF] = {0, 1, 1, 2, 2};
  static constexpr int DY[NV] = {0, 1};
  static constexpr int DX[NV] = {0, 0};
};
template <> struct CI<3> {  // ho odd, wo odd
  static constexpr int NV = 4, NF = 14;
  static constexpr int L[NF] = {0, 2, 6, 8, 17, 21, 23, 39, 41, 44, 45, 47, 51, 53};
  static constexpr int A[NF] = {0, 0, 0, 0, 1, 1, 1, 2, 2, 3, 0, 1, 2, 3};
  static constexpr int Bb[NF] = {0, 1, 2, 3, 1, 2, 3, 2, 3, 3, 4, 4, 4, 4};
  static constexpr int DY[NV] = {0, 0, 1, 1};
  static constexpr int DX[NV] = {0, 1, 0, 1};
};

// Packed f32x8 -> bf16x8 (RNE via hardware v_cvt_pk_bf16_f32; let the
// compiler lower the cast rather than hand-writing the asm).
__device__ __forceinline__ short8 cvt8(floatx8 v) {
  return __builtin_bit_cast(short8, __builtin_convertvector(v, bf16x8));
}

template <int CLS>
__device__ __forceinline__ void body(const float* __restrict__ x,
                                     const float* __restrict__ kern,
                                     float* __restrict__ out, int b, int hi0,
                                     int wi0) {
  using I = CI<CLS>;
  constexpr int NV = I::NV, NF = I::NF;
  const int tid = threadIdx.x;
  const int wave = tid >> 6, lane = tid & 63;
  const int quad = lane >> 4, l16 = lane & 15;
  const int mb = (wave & 1) * 16;   // wave's m-block (pixels)
  const int nh = (wave >> 1) * 32;  // wave's n-half (couts)
  const int m = mb + l16;           // A-operand row: m = lane&15
  const int ph = m >> 3, pw = m & 7;
  const int c8 = quad * 8;          // A/B k-offset within chalf: k = quad*8 + j

  floatx4 acc0 = {0.f, 0.f, 0.f, 0.f};
  floatx4 acc1 = {0.f, 0.f, 0.f, 0.f};

  short8 ones;  // bf16(1.0) splat for the bias ("ones") feature
#pragma unroll
  for (int j = 0; j < 8; ++j) ones[j] = (short)0x3F80;

#pragma unroll
  for (int chalf = 0; chalf < 2; ++chalf) {
    const int c0 = chalf * 32;
    // Per-lane patch planes (8 channels each), direct from global.
    // x is 2.1 MB -> L2-resident; loads are coalesced (quad tiles the
    // channel row, l16 tiles 16 consecutive pixels). OOB lanes -> 0.
    float vpl[NV][8];
#pragma unroll
    for (int p = 0; p < NV; ++p) {
      const int hr = hi0 + ph + I::DY[p];
      const int wc = wi0 + pw + I::DX[p];
      float4 lo = make_float4(0.f, 0.f, 0.f, 0.f);
      float4 hi = lo;
      if (hr < 32 && wc < 32) {
        const float* s = &x[(((b * 32) + hr) * 32 + wc) * 64 + c0 + c8];
        lo = *(const float4*)s;
        hi = *(const float4*)(s + 4);
      }
      vpl[p][0] = lo.x; vpl[p][1] = lo.y; vpl[p][2] = lo.z; vpl[p][3] = lo.w;
      vpl[p][4] = hi.x; vpl[p][5] = hi.y; vpl[p][6] = hi.z; vpl[p][7] = hi.w;
    }
    // Feature loop, fully unrolled (f-indexed tables must constant-fold so
    // vpl stays in registers). f == NF is the bias/ones feature (row 54):
    // summed over both chalves it contributes exactly sum_c W[54][c][n].
#pragma unroll
    for (int f = 0; f <= NF; ++f) {
      const int lrow = (f == NF) ? kBiasL : I::L[f];
      // B-fragments straight from kern (901 KB, L2-resident, shared by all
      // blocks of this class): 16 dword loads off one base, imm offsets.
      const float* wb = kern + (lrow * 64 + c0 + c8) * 64 + nh + l16;
      floatx8 w0, w1;
#pragma unroll
      for (int j = 0; j < 8; ++j) {
        w0[j] = wb[j * 64];       // n = nh + l16
        w1[j] = wb[j * 64 + 16];  // n = nh + 16 + l16
      }
      const short8 bf0 = cvt8(w0);
      const short8 bf1 = cvt8(w1);
      short8 afrag;
      if (f == NF) {
        afrag = ones;
      } else {
        floatx8 av;
#pragma unroll
        for (int j = 0; j < 8; ++j) {
          const float va = vpl[I::A[f]][j];
          av[j] = (I::Bb[f] == NV) ? va : va * vpl[I::Bb[f]][j];
        }
        afrag = cvt8(av);
      }
      acc0 = __builtin_amdgcn_mfma_f32_16x16x32_bf16(afrag, bf0, acc0, 0, 0, 0);
      acc1 = __builtin_amdgcn_mfma_f32_16x16x32_bf16(afrag, bf1, acc1, 0, 0, 0);
    }
  }

  // Epilogue. D: col = n = lane&15 group, row = quad*4 + reg.
  constexpr int rh = CLS >> 1, rw = CLS & 1;
#pragma unroll
  for (int nt = 0; nt < 2; ++nt) {
    const int n = nh + nt * 16 + l16;
    const floatx4 a = nt ? acc1 : acc0;
#pragma unroll
    for (int r = 0; r < 4; ++r) {
      const int mm = mb + quad * 4 + r;
      const int hi = hi0 + (mm >> 3), wi = wi0 + (mm & 7);
      out[(((b * 64) + (2 * hi + rh)) * 64 + (2 * wi + rw)) * 64 + n] = a[r];
    }
  }
}

__global__ __launch_bounds__(256, 4) void qct_main(const float* __restrict__ x,
                                                   const float* __restrict__ kern,
                                                   float* __restrict__ out) {
  const int bid = blockIdx.x;
  // Longest-job-first across CUs (7:1 per-class work ratio): first 256
  // blocks (one per CU) are class 3, so each CU gets ~one block per class.
  int cls, blk;
  if (bid < 256)      { cls = 3; blk = bid; }
  else if (bid < 512) { cls = 1; blk = bid - 256; }
  else if (bid < 768) { cls = 2; blk = bid - 512; }
  else                { cls = 0; blk = bid - 768; }
  const int b = blk >> 5, tile = blk & 31;
  const int hi0 = (tile >> 2) * 4;  // 4x8 class-space tile = 32 pixels
  const int wi0 = (tile & 3) * 8;
  switch (cls) {
    case 0: body<0>(x, kern, out, b, hi0, wi0); break;
    case 1: body<1>(x, kern, out, b, hi0, wi0); break;
    case 2: body<2>(x, kern, out, b, hi0, wi0); break;
    case 3: body<3>(x, kern, out, b, hi0, wi0); break;
  }
}

extern "C" void kernel_launch(void* const* d_in, const int* in_sizes, int n_in,
                              void* d_out, int out_size, void* d_ws,
                              size_t ws_size, hipStream_t stream) {
  const float* x = (const float*)d_in[0];     // [8,32,32,64] f32
  const float* kern = (const float*)d_in[1];  // [55,64,64]   f32
  float* out = (float*)d_out;                 // [8,64,64,64] f32
  // Single dispatch; bias folded into the GEMM as a ones-feature, ws unused.
  qct_main<<<1024, 256, 0, stream>>>(x, kern, out);
}

// Round 3
// 68.043 us; speedup vs baseline: 1.0826x; 1.0234x over previous
//
#include <hip/hip_runtime.h>
#include <stdint.h>

// QuadraticConv2DTranspose via per-parity-class bf16 MFMA GEMM.
//
// Bed-of-nails stride-2 upsample => per output-parity class only 2/5/5/14 of
// the 55 features are live. Cast as 4 GEMMs:
//   out[m,n] = sum_k F[m,k] * W[k,n],  k = f*64 + c
// with the bias row (L=54) folded in as an extra "ones" feature.
//
// v2 (resubmit; round-2 bench was an infra failure, not a kernel fault):
// W is pre-transposed ONCE into the workspace as bf16 in MFMA B-fragment
// order Wt[l][chalf][quad][n][k8]. v1 re-loaded W per feature as 16 strided
// f32 dword-gathers + 8 v_cvt_pk per wave, replicated 512x across
// blocks/waves for the same 240 KB -> hot loop was L2-request/latency bound
// on W. Now each B-fragment is ONE coalesced global_load_dwordx4 (64 lanes
// x 16 B = 1 KiB in 4 contiguous 256 B segments), W bytes halve (bf16), and
// conversion happens once chip-wide. Hot loop per feature: 2 VMEM + ~12
// VALU + 2 MFMA. ws usage 450 KB (ws is ~256 MiB per the harness poison
// fills); prep rewrites Wt every launch so ws re-poisoning is safe.

typedef __attribute__((ext_vector_type(8))) short short8;
typedef __attribute__((ext_vector_type(8))) float floatx8;
typedef __attribute__((ext_vector_type(8))) __bf16 bf16x8;
typedef __attribute__((ext_vector_type(4))) float floatx4;

namespace {
constexpr int kBiasL = 54;
}

// Per-class tables. Patch value j = x[hi+DY[j], wi+DX[j]].
// Feature f: kernel row L[f], value v[A[f]]*v[Bb[f]]; Bb[f]==NV -> linear (v[A]).
template <int CLS> struct CI;
template <> struct CI<0> {  // ho even, wo even
  static constexpr int NV = 1, NF = 2;
  static constexpr int L[NF] = {30, 49};
  static constexpr int A[NF] = {0, 0};
  static constexpr int Bb[NF] = {0, 1};
  static constexpr int DY[NV] = {0};
  static constexpr int DX[NV] = {0};
};
template <> struct CI<1> {  // ho even, wo odd
  static constexpr int NV = 2, NF = 5;
  static constexpr int L[NF] = {24, 26, 35, 48, 50};
  static constexpr int A[NF] = {0, 0, 1, 0, 1};
  static constexpr int Bb[NF] = {0, 1, 1, 2, 2};
  static constexpr int DY[NV] = {0, 0};
  static constexpr int DX[NV] = {0, 1};
};
template <> struct CI<2> {  // ho odd, wo even
  static constexpr int NV = 2, NF = 5;
  static constexpr int L[NF] = {9, 15, 42, 46, 52};
  static constexpr int A[NF] = {0, 0, 1, 0, 1};
  static constexpr int Bb[NF] = {0, 1, 1, 2, 2};
  static constexpr int DY[NV] = {0, 1};
  static constexpr int DX[NV] = {0, 0};
};
template <> struct CI<3> {  // ho odd, wo odd
  static constexpr int NV = 4, NF = 14;
  static constexpr int L[NF] = {0, 2, 6, 8, 17, 21, 23, 39, 41, 44, 45, 47, 51, 53};
  static constexpr int A[NF] = {0, 0, 0, 0, 1, 1, 1, 2, 2, 3, 0, 1, 2, 3};
  static constexpr int Bb[NF] = {0, 1, 2, 3, 1, 2, 3, 2, 3, 3, 4, 4, 4, 4};
  static constexpr int DY[NV] = {0, 0, 1, 1};
  static constexpr int DX[NV] = {0, 1, 0, 1};
};

// Packed f32x8 -> bf16x8 (RNE via hardware v_cvt_pk_bf16_f32; compiler
// lowers the cast -- same numerics as the passing v1 kernel).
__device__ __forceinline__ short8 cvt8(floatx8 v) {
  return __builtin_bit_cast(short8, __builtin_convertvector(v, bf16x8));
}

// Wt[l][ch][q][n][j] = bf16(kern[l][ch*32 + q*8 + j][n]); 55*2*4*64*8 shorts
// = 450 KB in ws. Per (l,ch,q): lane n reads 8 strided dwords (each j a
// contiguous 256 B row across lanes) and emits one short8 (16 B) store.
__global__ __launch_bounds__(256) void prep_kernel(const float* __restrict__ kern,
                                                   short* __restrict__ wt) {
  const int l = blockIdx.x >> 1, ch = blockIdx.x & 1;
  const int q = threadIdx.x >> 6, n = threadIdx.x & 63;
  const float* src = &kern[(size_t)(l * 64 + ch * 32 + q * 8) * 64 + n];
  floatx8 v;
#pragma unroll
  for (int j = 0; j < 8; ++j) v[j] = src[j * 64];
  *(short8*)&wt[(size_t)(((l * 2 + ch) * 4 + q) * 64 + n) * 8] = cvt8(v);
}

template <int CLS>
__device__ __forceinline__ void body(const float* __restrict__ x,
                                     const short8* __restrict__ wt,
                                     float* __restrict__ out, int b, int hi0,
                                     int wi0) {
  using I = CI<CLS>;
  constexpr int NV = I::NV, NF = I::NF;
  const int tid = threadIdx.x;
  const int wave = tid >> 6, lane = tid & 63;
  const int quad = lane >> 4, l16 = lane & 15;
  const int mb = (wave & 1) * 16;   // wave's m-block (pixels)
  const int nh = (wave >> 1) * 32;  // wave's n-half (couts)
  const int m = mb + l16;           // A-operand row: m = lane&15
  const int ph = m >> 3, pw = m & 7;
  const int c8 = quad * 8;          // A/B k-offset within chalf: k = quad*8 + j

  floatx4 acc0 = {0.f, 0.f, 0.f, 0.f};
  floatx4 acc1 = {0.f, 0.f, 0.f, 0.f};

  short8 ones;  // bf16(1.0) splat for the bias ("ones") feature
#pragma unroll
  for (int j = 0; j < 8; ++j) ones[j] = (short)0x3F80;

#pragma unroll
  for (int chalf = 0; chalf < 2; ++chalf) {
    const int c0 = chalf * 32;
    // Per-lane patch planes (8 channels each), direct from global.
    // x is 2.1 MB -> L2-resident; loads are coalesced. OOB lanes -> 0.
    float vpl[NV][8];
#pragma unroll
    for (int p = 0; p < NV; ++p) {
      const int hr = hi0 + ph + I::DY[p];
      const int wc = wi0 + pw + I::DX[p];
      float4 lo = make_float4(0.f, 0.f, 0.f, 0.f);
      float4 hi = lo;
      if (hr < 32 && wc < 32) {
        const float* s = &x[(((b * 32) + hr) * 32 + wc) * 64 + c0 + c8];
        lo = *(const float4*)s;
        hi = *(const float4*)(s + 4);
      }
      vpl[p][0] = lo.x; vpl[p][1] = lo.y; vpl[p][2] = lo.z; vpl[p][3] = lo.w;
      vpl[p][4] = hi.x; vpl[p][5] = hi.y; vpl[p][6] = hi.z; vpl[p][7] = hi.w;
    }
    // Feature loop, fully unrolled (tables constant-fold; vpl stays in
    // registers). f == NF is the bias/ones feature (row 54): summed over
    // both chalves it contributes exactly sum_c W[54][c][n].
#pragma unroll
    for (int f = 0; f <= NF; ++f) {
      const int lrow = (f == NF) ? kBiasL : I::L[f];
      // B-fragments: one coalesced 16 B load each from fragment-ordered Wt.
      const short8* wrow =
          wt + (size_t)((lrow * 2 + chalf) * 4 + quad) * 64 + nh + l16;
      const short8 bf0 = wrow[0];   // n = nh + l16
      const short8 bf1 = wrow[16];  // n = nh + 16 + l16
      short8 afrag;
      if (f == NF) {
        afrag = ones;
      } else {
        floatx8 av;
#pragma unroll
        for (int j = 0; j < 8; ++j) {
          const float va = vpl[I::A[f]][j];
          av[j] = (I::Bb[f] == NV) ? va : va * vpl[I::Bb[f]][j];
        }
        afrag = cvt8(av);
      }
      acc0 = __builtin_amdgcn_mfma_f32_16x16x32_bf16(afrag, bf0, acc0, 0, 0, 0);
      acc1 = __builtin_amdgcn_mfma_f32_16x16x32_bf16(afrag, bf1, acc1, 0, 0, 0);
    }
  }

  // Epilogue. D: col = n = lane&15 group, row = quad*4 + reg.
  constexpr int rh = CLS >> 1, rw = CLS & 1;
#pragma unroll
  for (int nt = 0; nt < 2; ++nt) {
    const int n = nh + nt * 16 + l16;
    const floatx4 a = nt ? acc1 : acc0;
#pragma unroll
    for (int r = 0; r < 4; ++r) {
      const int mm = mb + quad * 4 + r;
      const int hi = hi0 + (mm >> 3), wi = wi0 + (mm & 7);
      out[(((b * 64) + (2 * hi + rh)) * 64 + (2 * wi + rw)) * 64 + n] = a[r];
    }
  }
}

__global__ __launch_bounds__(256, 4) void qct_main(const float* __restrict__ x,
                                                   const short8* __restrict__ wt,
                                                   float* __restrict__ out) {
  const int bid = blockIdx.x;
  // Longest-job-first across CUs (7:1 per-class work ratio): first 256
  // blocks (one per CU) are class 3, so each CU gets ~one block per class.
  int cls, blk;
  if (bid < 256)      { cls = 3; blk = bid; }
  else if (bid < 512) { cls = 1; blk = bid - 256; }
  else if (bid < 768) { cls = 2; blk = bid - 512; }
  else                { cls = 0; blk = bid - 768; }
  const int b = blk >> 5, tile = blk & 31;
  const int hi0 = (tile >> 2) * 4;  // 4x8 class-space tile = 32 pixels
  const int wi0 = (tile & 3) * 8;
  switch (cls) {
    case 0: body<0>(x, wt, out, b, hi0, wi0); break;
    case 1: body<1>(x, wt, out, b, hi0, wi0); break;
    case 2: body<2>(x, wt, out, b, hi0, wi0); break;
    case 3: body<3>(x, wt, out, b, hi0, wi0); break;
  }
}

extern "C" void kernel_launch(void* const* d_in, const int* in_sizes, int n_in,
                              void* d_out, int out_size, void* d_ws,
                              size_t ws_size, hipStream_t stream) {
  const float* x = (const float*)d_in[0];     // [8,32,32,64] f32
  const float* kern = (const float*)d_in[1];  // [55,64,64]   f32
  float* out = (float*)d_out;                 // [8,64,64,64] f32
  short* wt = (short*)d_ws;                   // 450 KB bf16 Wt scratch

  prep_kernel<<<110, 256, 0, stream>>>(kern, wt);
  qct_main<<<1024, 256, 0, stream>>>(x, (const short8*)wt, out);
}

// Round 4
// 67.821 us; speedup vs baseline: 1.0862x; 1.0033x over previous
//
#include <hip/hip_runtime.h>
#include <stdint.h>

// QuadraticConv2DTranspose via per-parity-class bf16 MFMA GEMM.
//
// Bed-of-nails stride-2 upsample => per output-parity class only 2/5/5/14 of
// the 55 features are live. Cast as 4 GEMMs:
//   out[m,n] = sum_k F[m,k] * W[k,n],  k = f*64 + c
// with the bias row (L=54) folded in as an extra "ones" feature.
//
// v3 (this round): SINGLE dispatch. Rounds 0-3 showed the hot-loop
// instruction stream is not the dominant term; per-dispatch launch cost
// (~3-4 us each) and W L2 re-reads are. So the separate Wt-prep kernel is
// gone: each block stages its own W slice into LDS in MFMA B-fragment
// order sW[f][quad][n][j8] (bf16), converted from kern with fully
// coalesced f32 row loads, once per channel-half. Hot loop reads B-frags
// via ds_read_b128 (16-lane-contiguous 256 B groups -> conflict-free).
// Costs: 3 barriers + 60 KB LDS (2 blocks/CU) -- fine, the B-path no
// longer needs global-latency hiding. No workspace use at all.

typedef __attribute__((ext_vector_type(8))) short short8;
typedef __attribute__((ext_vector_type(8))) float floatx8;
typedef __attribute__((ext_vector_type(8))) __bf16 bf16x8;
typedef __attribute__((ext_vector_type(4))) float floatx4;

namespace {
constexpr int kBiasL = 54;
constexpr int kMaxF = 15;  // class-3 live features + bias row
}

// Per-class tables. Patch value j = x[hi+DY[j], wi+DX[j]].
// Feature f: kernel row L[f], value v[A[f]]*v[Bb[f]]; Bb[f]==NV -> linear (v[A]).
template <int CLS> struct CI;
template <> struct CI<0> {  // ho even, wo even
  static constexpr int NV = 1, NF = 2;
  static constexpr int L[NF] = {30, 49};
  static constexpr int A[NF] = {0, 0};
  static constexpr int Bb[NF] = {0, 1};
  static constexpr int DY[NV] = {0};
  static constexpr int DX[NV] = {0};
};
template <> struct CI<1> {  // ho even, wo odd
  static constexpr int NV = 2, NF = 5;
  static constexpr int L[NF] = {24, 26, 35, 48, 50};
  static constexpr int A[NF] = {0, 0, 1, 0, 1};
  static constexpr int Bb[NF] = {0, 1, 1, 2, 2};
  static constexpr int DY[NV] = {0, 0};
  static constexpr int DX[NV] = {0, 1};
};
template <> struct CI<2> {  // ho odd, wo even
  static constexpr int NV = 2, NF = 5;
  static constexpr int L[NF] = {9, 15, 42, 46, 52};
  static constexpr int A[NF] = {0, 0, 1, 0, 1};
  static constexpr int Bb[NF] = {0, 1, 1, 2, 2};
  static constexpr int DY[NV] = {0, 1};
  static constexpr int DX[NV] = {0, 0};
};
template <> struct CI<3> {  // ho odd, wo odd
  static constexpr int NV = 4, NF = 14;
  static constexpr int L[NF] = {0, 2, 6, 8, 17, 21, 23, 39, 41, 44, 45, 47, 51, 53};
  static constexpr int A[NF] = {0, 0, 0, 0, 1, 1, 1, 2, 2, 3, 0, 1, 2, 3};
  static constexpr int Bb[NF] = {0, 1, 2, 3, 1, 2, 3, 2, 3, 3, 4, 4, 4, 4};
  static constexpr int DY[NV] = {0, 0, 1, 1};
  static constexpr int DX[NV] = {0, 1, 0, 1};
};

// Packed f32x8 -> bf16x8 (RNE via hardware v_cvt_pk_bf16_f32; compiler
// lowers the cast -- same numerics as the passing kernels).
__device__ __forceinline__ short8 cvt8(floatx8 v) {
  return __builtin_bit_cast(short8, __builtin_convertvector(v, bf16x8));
}

template <int CLS>
__device__ __forceinline__ void body(const float* __restrict__ x,
                                     const float* __restrict__ kern,
                                     float* __restrict__ out, int b, int hi0,
                                     int wi0, short* __restrict__ sW) {
  using I = CI<CLS>;
  constexpr int NV = I::NV, NF = I::NF;
  const int tid = threadIdx.x;
  const int wave = tid >> 6, lane = tid & 63;
  const int quad = lane >> 4, l16 = lane & 15;
  const int mb = (wave & 1) * 16;   // wave's m-block (pixels)
  const int nh = (wave >> 1) * 32;  // wave's n-half (couts)
  const int m = mb + l16;           // A-operand row: m = lane&15
  const int ph = m >> 3, pw = m & 7;
  const int c8 = quad * 8;          // A/B k-offset within chalf: k = quad*8 + j

  floatx4 acc0 = {0.f, 0.f, 0.f, 0.f};
  floatx4 acc1 = {0.f, 0.f, 0.f, 0.f};

  short8 ones;  // bf16(1.0) splat for the bias ("ones") feature
#pragma unroll
  for (int j = 0; j < 8; ++j) ones[j] = (short)0x3F80;

  // Staging role: thread owns (quad g, column n); per step it converts one
  // (feature, k8-quad) strip of W: 8 coalesced 256 B row loads + 1
  // ds_write_b128 into fragment order sW[(f*4+g)*64 + n][j8].
  const int sg = tid >> 6, sn = tid & 63;

#pragma unroll
  for (int chalf = 0; chalf < 2; ++chalf) {
    const int c0 = chalf * 32;
    if (chalf) __syncthreads();  // all reads of sW[ch0] done before restage
    // ---- stage W slice for this chalf into LDS (bf16, fragment order) ----
#pragma unroll
    for (int f = 0; f <= NF; ++f) {
      const int lrow = (f == NF) ? kBiasL : I::L[f];
      const float* src = &kern[(size_t)(lrow * 64 + c0 + sg * 8) * 64 + sn];
      floatx8 v;
#pragma unroll
      for (int j = 0; j < 8; ++j) v[j] = src[j * 64];
      *(short8*)&sW[((f * 4 + sg) * 64 + sn) * 8] = cvt8(v);
    }
    __syncthreads();

    // ---- per-lane patch planes (8 channels each), direct from global ----
    float vpl[NV][8];
#pragma unroll
    for (int p = 0; p < NV; ++p) {
      const int hr = hi0 + ph + I::DY[p];
      const int wc = wi0 + pw + I::DX[p];
      float4 lo = make_float4(0.f, 0.f, 0.f, 0.f);
      float4 hi = lo;
      if (hr < 32 && wc < 32) {
        const float* s = &x[(((b * 32) + hr) * 32 + wc) * 64 + c0 + c8];
        lo = *(const float4*)s;
        hi = *(const float4*)(s + 4);
      }
      vpl[p][0] = lo.x; vpl[p][1] = lo.y; vpl[p][2] = lo.z; vpl[p][3] = lo.w;
      vpl[p][4] = hi.x; vpl[p][5] = hi.y; vpl[p][6] = hi.z; vpl[p][7] = hi.w;
    }

    // ---- feature loop, fully unrolled; B-frags via ds_read_b128 ----
#pragma unroll
    for (int f = 0; f <= NF; ++f) {
      const short8 bf0 = *(const short8*)&sW[((f * 4 + quad) * 64 + nh + l16) * 8];
      const short8 bf1 =
          *(const short8*)&sW[((f * 4 + quad) * 64 + nh + 16 + l16) * 8];
      short8 afrag;
      if (f == NF) {
        afrag = ones;
      } else {
        floatx8 av;
#pragma unroll
        for (int j = 0; j < 8; ++j) {
          const float va = vpl[I::A[f]][j];
          av[j] = (I::Bb[f] == NV) ? va : va * vpl[I::Bb[f]][j];
        }
        afrag = cvt8(av);
      }
      acc0 = __builtin_amdgcn_mfma_f32_16x16x32_bf16(afrag, bf0, acc0, 0, 0, 0);
      acc1 = __builtin_amdgcn_mfma_f32_16x16x32_bf16(afrag, bf1, acc1, 0, 0, 0);
    }
  }

  // Epilogue. D: col = n = lane&15 group, row = quad*4 + reg.
  constexpr int rh = CLS >> 1, rw = CLS & 1;
#pragma unroll
  for (int nt = 0; nt < 2; ++nt) {
    const int n = nh + nt * 16 + l16;
    const floatx4 a = nt ? acc1 : acc0;
#pragma unroll
    for (int r = 0; r < 4; ++r) {
      const int mm = mb + quad * 4 + r;
      const int hi = hi0 + (mm >> 3), wi = wi0 + (mm & 7);
      out[(((b * 64) + (2 * hi + rh)) * 64 + (2 * wi + rw)) * 64 + n] = a[r];
    }
  }
}

__global__ __launch_bounds__(256, 2) void qct_main(const float* __restrict__ x,
                                                   const float* __restrict__ kern,
                                                   float* __restrict__ out) {
  // 60 KB: max over classes of (NF+1)*4*64*8 bf16 fragment slots.
  __shared__ short sW[kMaxF * 4 * 64 * 8];
  const int bid = blockIdx.x;
  // Longest-job-first across CUs (7:1 per-class work ratio): first 256
  // blocks are class 3, so heavy blocks start first and light classes
  // backfill as they finish (2 blocks/CU resident at 60 KB LDS).
  int cls, blk;
  if (bid < 256)      { cls = 3; blk = bid; }
  else if (bid < 512) { cls = 1; blk = bid - 256; }
  else if (bid < 768) { cls = 2; blk = bid - 512; }
  else                { cls = 0; blk = bid - 768; }
  const int b = blk >> 5, tile = blk & 31;
  const int hi0 = (tile >> 2) * 4;  // 4x8 class-space tile = 32 pixels
  const int wi0 = (tile & 3) * 8;
  switch (cls) {
    case 0: body<0>(x, kern, out, b, hi0, wi0, sW); break;
    case 1: body<1>(x, kern, out, b, hi0, wi0, sW); break;
    case 2: body<2>(x, kern, out, b, hi0, wi0, sW); break;
    case 3: body<3>(x, kern, out, b, hi0, wi0, sW); break;
  }
}

extern "C" void kernel_launch(void* const* d_in, const int* in_sizes, int n_in,
                              void* d_out, int out_size, void* d_ws,
                              size_t ws_size, hipStream_t stream) {
  const float* x = (const float*)d_in[0];     // [8,32,32,64] f32
  const float* kern = (const float*)d_in[1];  // [55,64,64]   f32
  float* out = (float*)d_out;                 // [8,64,64,64] f32
  // Single dispatch; W staged per-block into LDS; bias folded as a ones
  // feature; workspace unused.
  qct_main<<<1024, 256, 0, stream>>>(x, kern, out);
}